// Round 16
// baseline (125.540 us; speedup 1.0000x reference)
//
#include <hip/hip_runtime.h>
#include <cstdint>
#include <cstddef>

// ---- constants from the reference config (exact fp32 images of the Python doubles) ----
#define C_DECAY 0.99f   // (1.0 - alpha), alpha = 1.0/100.0
#define C_ALPHA 0.01f   // alpha
#define C_THR   0.58f   // IGNITE_THR
#define C_WTA   0.85f   // WTA_INH

#define NPB   16        // neurons per phase1 block (64B per spike row slice)
#define TILE  512       // timesteps per LDS tile (phase1); 32 KiB per buffer

// EMA step: EXACT replica of the reference op order. DO NOT rewrite algebraically
// (R10 lesson: fmaf substitution broke bitwise equality despite a paper proof).
#define EMA_STEP(x) nmda = __fadd_rn(__fmul_rn(C_DECAY, nmda), __fmul_rn(C_ALPHA, (x)))

typedef const __attribute__((address_space(1))) void g_void;
typedef __attribute__((address_space(3))) void l_void;
typedef float f32x4 __attribute__((ext_vector_type(4)));

// async global->LDS DMA, 16B/lane, wave-uniform LDS base (lane i lands at base + i*16)
__device__ __forceinline__ void gload_lds16(const float* g, float* l) {
  __builtin_amdgcn_global_load_lds((g_void*)g, (l_void*)l, 16, 0, 0);
}

// ---------------- Phase 1: exact EMA chains; mid-chunk state staged in registers ----------------
// grid: N/16 = 256 blocks; block: 128 threads (wave0 = compute, wave1 = async loader)
// [R13/R14 lesson: NO stores inside the chain; save state to a reg, cluster stores at group end]
__global__ __launch_bounds__(128)
void gw_phase1(const float* __restrict__ spikes, const float* __restrict__ nmda0,
               float* __restrict__ bnd, float* __restrict__ nmf,
               int T, int N, int Ls) {
  __shared__ float sb[2][TILE * NPB];   // 2 x 32 KiB, linear [step][neuron]
  const int w    = threadIdx.x >> 6;
  const int lane = threadIdx.x & 63;
  const int nblk = gridDim.x;                       // N/NPB
  const int bs   = (nblk % 8 == 0) ? ((blockIdx.x & 7) * (nblk >> 3) + (blockIdx.x >> 3))
                                   : (int)blockIdx.x;
  const int n0   = bs * NPB;
  const int ntiles = T / TILE;
  const int Lm1  = (1 << Ls) - 1;
  const int grow = lane >> 2;        // row within a 16-row DMA group
  const int gc   = (lane & 3) * 4;   // float column within the 16-float row

  if (w == 1) {   // prologue: stage tile 0 (32 x 1KiB async DMAs)
#pragma unroll
    for (int j = 0; j < TILE / 16; ++j)
      gload_lds16(spikes + (size_t)(j * 16 + grow) * N + n0 + gc, &sb[0][j * 256]);
  }
  __syncthreads();   // drains vmcnt -> tile 0 resident

  const int nn = lane & (NPB - 1);   // 4 lanes duplicate each neuron (broadcast reads)
  float nmda = 0.0f;
  if (w == 0) nmda = nmda0[n0 + nn];

  for (int tile = 0; tile < ntiles; ++tile) {
    const int cur = tile & 1;
    if (w == 0) {
      const float* buf = sb[cur];
      const int t0 = tile * TILE;
      float tA[16], tB[16];
#pragma unroll
      for (int i = 0; i < 16; ++i) tA[i] = buf[i * NPB + nn];
#pragma unroll
      for (int jp = 0; jp < TILE / 32; ++jp) {
        // ---- even group (steps tb..tb+15): prefetch odd group, chain, clustered stores ----
        {
#pragma unroll
          for (int i = 0; i < 16; ++i) tB[i] = buf[((2 * jp + 1) * 16 + i) * NPB + nn];
          const int tb = t0 + 2 * jp * 16;
          const float save0 = nmda;          // state before step tb (off-chain copy)
#pragma unroll
          for (int i = 0; i < 8; ++i) EMA_STEP(tA[i]);
          const float save1 = nmda;          // state before step tb+8
#pragma unroll
          for (int i = 8; i < 16; ++i) EMA_STEP(tA[i]);
          // clustered boundary stores (off the dependent chain)
          if ((tb & Lm1) == 0 && lane < NPB)
            bnd[(size_t)(tb >> Ls) * N + n0 + lane] = save0;
          if (((tb + 8) & Lm1) == 0 && lane < NPB)
            bnd[(size_t)((tb + 8) >> Ls) * N + n0 + lane] = save1;
        }
        // ---- odd group (steps tc..tc+15): prefetch next even group, chain, stores ----
        {
          if (jp < TILE / 32 - 1) {
#pragma unroll
            for (int i = 0; i < 16; ++i) tA[i] = buf[((2 * jp + 2) * 16 + i) * NPB + nn];
          }
          const int tc = t0 + (2 * jp + 1) * 16;
          const float save0 = nmda;
#pragma unroll
          for (int i = 0; i < 8; ++i) EMA_STEP(tB[i]);
          const float save1 = nmda;
#pragma unroll
          for (int i = 8; i < 16; ++i) EMA_STEP(tB[i]);
          if ((tc & Lm1) == 0 && lane < NPB)
            bnd[(size_t)(tc >> Ls) * N + n0 + lane] = save0;
          if (((tc + 8) & Lm1) == 0 && lane < NPB)
            bnd[(size_t)((tc + 8) >> Ls) * N + n0 + lane] = save1;
        }
      }
    } else if (tile + 1 < ntiles) {
      const int t0 = (tile + 1) * TILE;
#pragma unroll
      for (int j = 0; j < TILE / 16; ++j)
        gload_lds16(spikes + (size_t)(t0 + j * 16 + grow) * N + n0 + gc, &sb[cur ^ 1][j * 256]);
    }
    __syncthreads();
  }
  if (w == 0 && lane < NPB) nmf[n0 + lane] = nmda;
}

// lexicographic merge of two (score desc, index asc) top-2 tuples
__device__ __forceinline__ void merge2(float& a1, int& i1, float& a2, int& i2,
                                       float b1, int j1, float b2, int j2) {
  const bool afirst = (a1 > b1) || (a1 == b1 && i1 < j1);
  const float w1 = afirst ? a1 : b1; const int wi1 = afirst ? i1 : j1;
  const float l1 = afirst ? b1 : a1; const int li1 = afirst ? j1 : i1;
  const float cc = afirst ? a2 : b2; const int ci  = afirst ? i2 : j2;
  const bool sfirst = (cc > l1) || (cc == l1 && ci < li1);
  a1 = w1; i1 = wi1;
  a2 = sfirst ? cc : l1; i2 = sfirst ? ci : li1;
}

// local stable top-2 update with a new (score, idx), idx processed in ascending order
#define LOCAL_TOP2(c, idx)                                         \
  if ((c) > a1) { a2 = a1; i2 = i1; a1 = (c); i1 = (idx); }        \
  else if ((c) > a2) { a2 = (c); i2 = (idx); }

// ---------------- Phase 2: [R13-verbatim, proven ~41us @ 1024 blocks] GR-row groups ----------------
// 512 threads; pass A: 3-round partial butterfly -> 64 candidates/row; pass B: GR/8 rows per wave.
template<int GR>
__global__ __launch_bounds__(512)
void gw_phase2(const float* __restrict__ spikes, const float* __restrict__ bnd,
               float* __restrict__ mask, float* __restrict__ cov,
               int T, int N, int L, float covval) {
  const int tid  = threadIdx.x;            // [0, 512)
  const int lane = tid & 63;
  const int wv   = tid >> 6;               // wave id [0,8)
  const int N4   = N >> 2;
  const int half = N4 >> 1;
  const float4* sp4 = (const float4*)spikes;
  f32x4* mk4 = (f32x4*)mask;

  __shared__ float ws1[GR][64]; __shared__ int wi1s[GR][64];
  __shared__ float ws2[GR][64]; __shared__ int wi2s[GR][64];
  __shared__ float wmx[GR][64];
  __shared__ int gj1[GR], gj2[GR];

  const int chunk = blockIdx.x;
  float4 nmA = ((const float4*)bnd)[(size_t)chunk * N4 + tid];
  float4 nmB = ((const float4*)bnd)[(size_t)chunk * N4 + tid + half];
  const int baseA = tid * 4;
  const int baseB = baseA + (N >> 1);
  const int t00   = chunk * L;
  const int cslot = wv * 8 + (lane >> 3);  // candidate slot (8-lane group id)

  for (int g = 0; g < L; g += GR) {
    const int tg = t00 + g;

    // ---------- pass A: GR rows, depth-4 ring prefetch, 3-round partial butterfly ----------
    float4 pA[4], pB[4];
#pragma unroll
    for (int r = 0; r < 4; ++r) {
      pA[r] = sp4[(size_t)(tg + r) * N4 + tid];
      pB[r] = sp4[(size_t)(tg + r) * N4 + tid + half];
    }
#pragma unroll
    for (int r = 0; r < GR; ++r) {
      const float4 s  = pA[r & 3];
      const float4 s2 = pB[r & 3];
      if (r < GR - 4) {   // refill the ring slot just consumed
        pA[r & 3] = sp4[(size_t)(tg + r + 4) * N4 + tid];
        pB[r & 3] = sp4[(size_t)(tg + r + 4) * N4 + tid + half];
      }

      // EXACT reference op order (no FMA, no reassociation)
      nmA.x = __fadd_rn(__fmul_rn(C_DECAY, nmA.x), __fmul_rn(C_ALPHA, s.x));
      nmA.y = __fadd_rn(__fmul_rn(C_DECAY, nmA.y), __fmul_rn(C_ALPHA, s.y));
      nmA.z = __fadd_rn(__fmul_rn(C_DECAY, nmA.z), __fmul_rn(C_ALPHA, s.z));
      nmA.w = __fadd_rn(__fmul_rn(C_DECAY, nmA.w), __fmul_rn(C_ALPHA, s.w));
      nmB.x = __fadd_rn(__fmul_rn(C_DECAY, nmB.x), __fmul_rn(C_ALPHA, s2.x));
      nmB.y = __fadd_rn(__fmul_rn(C_DECAY, nmB.y), __fmul_rn(C_ALPHA, s2.y));
      nmB.z = __fadd_rn(__fmul_rn(C_DECAY, nmB.z), __fmul_rn(C_ALPHA, s2.z));
      nmB.w = __fadd_rn(__fmul_rn(C_DECAY, nmB.w), __fmul_rn(C_ALPHA, s2.w));

      const float cA0 = __fmul_rn(nmA.x, C_WTA), cA1 = __fmul_rn(nmA.y, C_WTA);
      const float cA2 = __fmul_rn(nmA.z, C_WTA), cA3 = __fmul_rn(nmA.w, C_WTA);
      const float cB0 = __fmul_rn(nmB.x, C_WTA), cB1 = __fmul_rn(nmB.y, C_WTA);
      const float cB2 = __fmul_rn(nmB.z, C_WTA), cB3 = __fmul_rn(nmB.w, C_WTA);
      float mx = fmaxf(fmaxf(fmaxf(nmA.x, nmA.y), fmaxf(nmA.z, nmA.w)),
                       fmaxf(fmaxf(nmB.x, nmB.y), fmaxf(nmB.z, nmB.w)));

      float a1 = cA0; int i1 = baseA;
      float a2 = -__builtin_inff(); int i2 = 0x7fffffff;
      LOCAL_TOP2(cA1, baseA + 1); LOCAL_TOP2(cA2, baseA + 2); LOCAL_TOP2(cA3, baseA + 3);
      LOCAL_TOP2(cB0, baseB);     LOCAL_TOP2(cB1, baseB + 1);
      LOCAL_TOP2(cB2, baseB + 2); LOCAL_TOP2(cB3, baseB + 3);

      // partial butterfly: 3 rounds -> each 8-lane group holds its merged top-2
#pragma unroll
      for (int m = 1; m < 8; m <<= 1) {
        const float b1 = __shfl_xor(a1, m, 64); const int j1 = __shfl_xor(i1, m, 64);
        const float b2 = __shfl_xor(a2, m, 64); const int j2 = __shfl_xor(i2, m, 64);
        mx = fmaxf(mx, __shfl_xor(mx, m, 64));
        merge2(a1, i1, a2, i2, b1, j1, b2, j2);
      }
      if ((lane & 7) == 0) {
        ws1[r][cslot] = a1; wi1s[r][cslot] = i1;
        ws2[r][cslot] = a2; wi2s[r][cslot] = i2;
        wmx[r][cslot] = mx;
      }
    }
    __syncthreads();

    // ---------- pass B: each wave finishes GR/8 rows (64 candidates, 6-round butterfly) ----------
#pragma unroll
    for (int rr = 0; rr < GR / 8; ++rr) {
      const int row = wv * (GR / 8) + rr;
      float a1 = ws1[row][lane]; int i1 = wi1s[row][lane];
      float a2 = ws2[row][lane]; int i2 = wi2s[row][lane];
      float gm = wmx[row][lane];
#pragma unroll
      for (int m = 1; m < 64; m <<= 1) {
        const float b1 = __shfl_xor(a1, m, 64); const int j1 = __shfl_xor(i1, m, 64);
        const float b2 = __shfl_xor(a2, m, 64); const int j2 = __shfl_xor(i2, m, 64);
        gm = fmaxf(gm, __shfl_xor(gm, m, 64));
        merge2(a1, i1, a2, i2, b1, j1, b2, j2);
      }
      if (lane == 0) {
        const int ig = (gm >= C_THR) ? 1 : 0;
        gj1[row] = ig ? i1 : -1;        // -1 sentinel: nothing matches -> zero row
        gj2[row] = ig ? i2 : -1;
        cov[tg + row] = ig ? covval : 0.0f;
      }
    }
    __syncthreads();

    // ---------- pass C: stream out GR mask rows (nontemporal) ----------
#pragma unroll
    for (int r = 0; r < GR; ++r) {
      const int j1 = gj1[r], j2 = gj2[r];
      f32x4 v, u;
      v.x = (j1 == baseA     || j2 == baseA)     ? 1.0f : 0.0f;
      v.y = (j1 == baseA + 1 || j2 == baseA + 1) ? 1.0f : 0.0f;
      v.z = (j1 == baseA + 2 || j2 == baseA + 2) ? 1.0f : 0.0f;
      v.w = (j1 == baseA + 3 || j2 == baseA + 3) ? 1.0f : 0.0f;
      u.x = (j1 == baseB     || j2 == baseB)     ? 1.0f : 0.0f;
      u.y = (j1 == baseB + 1 || j2 == baseB + 1) ? 1.0f : 0.0f;
      u.z = (j1 == baseB + 2 || j2 == baseB + 2) ? 1.0f : 0.0f;
      u.w = (j1 == baseB + 3 || j2 == baseB + 3) ? 1.0f : 0.0f;
      __builtin_nontemporal_store(v, &mk4[(size_t)(tg + r) * N4 + tid]);
      __builtin_nontemporal_store(u, &mk4[(size_t)(tg + r) * N4 + tid + half]);
    }
    if (g + GR < L) __syncthreads();
  }
}

extern "C" void kernel_launch(void* const* d_in, const int* in_sizes, int n_in,
                              void* d_out, int out_size, void* d_ws, size_t ws_size,
                              hipStream_t stream) {
  const float* spikes = (const float*)d_in[0];
  const float* nmda0  = (const float*)d_in[1];
  const int N = in_sizes[1];
  const int T = in_sizes[0] / N;

  float* out  = (float*)d_out;
  float* mask = out;                               // [T, N]
  float* cov  = out + (size_t)T * N;               // [T]
  float* nmf  = cov + T;                           // [N]

  // boundary-state chunk length L = 1<<Ls; prefer Ls=3 (1024 phase2 blocks), shrink if ws small
  int Ls = 3;
  while (((size_t)(T >> Ls)) * (size_t)N * sizeof(float) > ws_size && Ls < 13) ++Ls;
  const int L = 1 << Ls;
  const int C = T >> Ls;
  float* bnd = (float*)d_ws;                       // [C, N]
  const float covval = 2.0f / (float)N;

  gw_phase1<<<N / NPB, 128, 0, stream>>>(spikes, nmda0, bnd, nmf, T, N, Ls);
  if (L % 8 == 0) gw_phase2<8><<<C, 512, 0, stream>>>(spikes, bnd, mask, cov, T, N, L, covval);
  else            gw_phase2<16><<<C, 512, 0, stream>>>(spikes, bnd, mask, cov, T, N, L, covval);
}

// Round 17
// 122.307 us; speedup vs baseline: 1.0264x; 1.0264x over previous
//
#include <hip/hip_runtime.h>
#include <cstdint>
#include <cstddef>

// ---- constants from the reference config (exact fp32 images of the Python doubles) ----
#define C_DECAY 0.99f   // (1.0 - alpha), alpha = 1.0/100.0
#define C_ALPHA 0.01f   // alpha
#define C_THR   0.58f   // IGNITE_THR
#define C_WTA   0.85f   // WTA_INH

#define NPB   16        // neurons per phase1 block (64B per spike row slice)
#define TILE  256       // timesteps per LDS tile (phase1); 16 KiB per buffer

// EMA step: EXACT replica of the reference op order. DO NOT rewrite algebraically
// (R10 lesson: fmaf substitution broke bitwise equality despite a paper proof).
#define EMA_STEP(x) nmda = __fadd_rn(__fmul_rn(C_DECAY, nmda), __fmul_rn(C_ALPHA, (x)))

typedef const __attribute__((address_space(1))) void g_void;
typedef __attribute__((address_space(3))) void l_void;
typedef float f32x4 __attribute__((ext_vector_type(4)));

// async global->LDS DMA, 16B/lane, wave-uniform LDS base (lane i lands at base + i*16)
__device__ __forceinline__ void gload_lds16(const float* g, float* l) {
  __builtin_amdgcn_global_load_lds((g_void*)g, (l_void*)l, 16, 0, 0);
}

// ---------------- Phase 1: [R11-verbatim, proven ~60us @ Ls=4] ----------------
// grid: N/16 = 256 blocks; block: 128 threads (wave0 = compute, wave1 = async loader)
// [R13/R14/R16 lesson: phase1 is ONLY fast in this exact form at Ls=4 — do not touch]
__global__ __launch_bounds__(128)
void gw_phase1(const float* __restrict__ spikes, const float* __restrict__ nmda0,
               float* __restrict__ bnd, float* __restrict__ nmf,
               int T, int N, int Ls) {
  __shared__ float sb[2][TILE * NPB];   // 2 x 16 KiB, linear [step][neuron]
  const int w    = threadIdx.x >> 6;
  const int lane = threadIdx.x & 63;
  const int nblk = gridDim.x;                       // N/NPB
  const int bs   = (nblk % 8 == 0) ? ((blockIdx.x & 7) * (nblk >> 3) + (blockIdx.x >> 3))
                                   : (int)blockIdx.x;
  const int n0   = bs * NPB;
  const int ntiles = T / TILE;
  const int Lm1  = (1 << Ls) - 1;
  const int grow = lane >> 2;        // row within a 16-row DMA group
  const int gc   = (lane & 3) * 4;   // float column within the 16-float row

  if (w == 1) {   // prologue: stage tile 0 (16 x 1KiB async DMAs)
#pragma unroll
    for (int j = 0; j < TILE / 16; ++j)
      gload_lds16(spikes + (size_t)(j * 16 + grow) * N + n0 + gc, &sb[0][j * 256]);
  }
  __syncthreads();   // drains vmcnt -> tile 0 resident

  const int nn = lane & (NPB - 1);   // 4 lanes duplicate each neuron (broadcast reads)
  float nmda = 0.0f;
  if (w == 0) nmda = nmda0[n0 + nn];

  for (int tile = 0; tile < ntiles; ++tile) {
    const int cur = tile & 1;
    if (w == 0) {
      const float* buf = sb[cur];
      const int t0 = tile * TILE;
      float tA[16], tB[16];
#pragma unroll
      for (int i = 0; i < 16; ++i) tA[i] = buf[i * NPB + nn];
#pragma unroll
      for (int jp = 0; jp < TILE / 32; ++jp) {
        // even group: consume tA, prefetch odd group into tB
#pragma unroll
        for (int i = 0; i < 16; ++i) tB[i] = buf[((2 * jp + 1) * 16 + i) * NPB + nn];
        { const int tb = t0 + 2 * jp * 16;
          if ((tb & Lm1) == 0 && lane < NPB) bnd[(size_t)(tb >> Ls) * N + n0 + lane] = nmda; }
#pragma unroll
        for (int i = 0; i < 16; ++i) EMA_STEP(tA[i]);
        // odd group: consume tB, prefetch next even group into tA
        if (jp < TILE / 32 - 1) {
#pragma unroll
          for (int i = 0; i < 16; ++i) tA[i] = buf[((2 * jp + 2) * 16 + i) * NPB + nn];
        }
        { const int tb = t0 + (2 * jp + 1) * 16;
          if ((tb & Lm1) == 0 && lane < NPB) bnd[(size_t)(tb >> Ls) * N + n0 + lane] = nmda; }
#pragma unroll
        for (int i = 0; i < 16; ++i) EMA_STEP(tB[i]);
      }
    } else if (tile + 1 < ntiles) {
      const int t0 = (tile + 1) * TILE;
#pragma unroll
      for (int j = 0; j < TILE / 16; ++j)
        gload_lds16(spikes + (size_t)(t0 + j * 16 + grow) * N + n0 + gc, &sb[cur ^ 1][j * 256]);
    }
    __syncthreads();
  }
  if (w == 0 && lane < NPB) nmf[n0 + lane] = nmda;
}

// lexicographic merge of two (score desc, index asc) top-2 tuples
__device__ __forceinline__ void merge2(float& a1, int& i1, float& a2, int& i2,
                                       float b1, int j1, float b2, int j2) {
  const bool afirst = (a1 > b1) || (a1 == b1 && i1 < j1);
  const float w1 = afirst ? a1 : b1; const int wi1 = afirst ? i1 : j1;
  const float l1 = afirst ? b1 : a1; const int li1 = afirst ? j1 : i1;
  const float cc = afirst ? a2 : b2; const int ci  = afirst ? i2 : j2;
  const bool sfirst = (cc > l1) || (cc == l1 && ci < li1);
  a1 = w1; i1 = wi1;
  a2 = sfirst ? cc : l1; i2 = sfirst ? ci : li1;
}

// local stable top-2 update with a new (score, idx), idx processed in ascending order
#define LOCAL_TOP2(c, idx)                                         \
  if ((c) > a1) { a2 = a1; i2 = i1; a1 = (c); i1 = (idx); }        \
  else if ((c) > a2) { a2 = (c); i2 = (idx); }

// exact EMA update of both float4 segments (reference op order)
#define EMA_ROW(sA, sB)                                                        \
  nmA.x = __fadd_rn(__fmul_rn(C_DECAY, nmA.x), __fmul_rn(C_ALPHA, (sA).x));    \
  nmA.y = __fadd_rn(__fmul_rn(C_DECAY, nmA.y), __fmul_rn(C_ALPHA, (sA).y));    \
  nmA.z = __fadd_rn(__fmul_rn(C_DECAY, nmA.z), __fmul_rn(C_ALPHA, (sA).z));    \
  nmA.w = __fadd_rn(__fmul_rn(C_DECAY, nmA.w), __fmul_rn(C_ALPHA, (sA).w));    \
  nmB.x = __fadd_rn(__fmul_rn(C_DECAY, nmB.x), __fmul_rn(C_ALPHA, (sB).x));    \
  nmB.y = __fadd_rn(__fmul_rn(C_DECAY, nmB.y), __fmul_rn(C_ALPHA, (sB).y));    \
  nmB.z = __fadd_rn(__fmul_rn(C_DECAY, nmB.z), __fmul_rn(C_ALPHA, (sB).z));    \
  nmB.w = __fadd_rn(__fmul_rn(C_DECAY, nmB.w), __fmul_rn(C_ALPHA, (sB).w));

// ---------------- Phase 2 (split): 2 blocks per 16-step chunk; odd block recomputes 8-row prefix ----------------
// grid: 2*C blocks; block: 512 threads (8 waves). Processes exactly 8 output rows.
__global__ __launch_bounds__(512)
void gw_phase2s(const float* __restrict__ spikes, const float* __restrict__ bnd,
                float* __restrict__ mask, float* __restrict__ cov,
                int T, int N, float covval) {
  const int tid  = threadIdx.x;            // [0, 512)
  const int lane = tid & 63;
  const int wv   = tid >> 6;               // wave id [0,8)
  const int N4   = N >> 2;
  const int half = N4 >> 1;
  const float4* sp4 = (const float4*)spikes;
  f32x4* mk4 = (f32x4*)mask;

  __shared__ float ws1[8][64]; __shared__ int wi1s[8][64];
  __shared__ float ws2[8][64]; __shared__ int wi2s[8][64];
  __shared__ float wmx[8][64];
  __shared__ int gj1[8], gj2[8];

  const int chunk = blockIdx.x >> 1;       // Ls=4 chunk id
  const int h     = blockIdx.x & 1;        // 0: rows 0..7, 1: rows 8..15 (with prefix recompute)
  float4 nmA = ((const float4*)bnd)[(size_t)chunk * N4 + tid];
  float4 nmB = ((const float4*)bnd)[(size_t)chunk * N4 + tid + half];
  const int baseA = tid * 4;
  const int baseB = baseA + (N >> 1);
  const int tc    = chunk * 16;            // chunk start step

  if (h) {
    // ---- prefix: redundantly recompute 8 EMA rows (loads + exact EMA only) ----
    float4 pA[4], pB[4];
#pragma unroll
    for (int r = 0; r < 4; ++r) {
      pA[r] = sp4[(size_t)(tc + r) * N4 + tid];
      pB[r] = sp4[(size_t)(tc + r) * N4 + tid + half];
    }
#pragma unroll
    for (int r = 0; r < 8; ++r) {
      const float4 s  = pA[r & 3];
      const float4 s2 = pB[r & 3];
      if (r < 4) {
        pA[r & 3] = sp4[(size_t)(tc + r + 4) * N4 + tid];
        pB[r & 3] = sp4[(size_t)(tc + r + 4) * N4 + tid + half];
      }
      EMA_ROW(s, s2);
    }
  }
  const int tg = tc + h * 8;               // first output row

  // ---------- pass A: 8 rows, depth-4 ring prefetch, 3-round partial butterfly ----------
  const int cslot = wv * 8 + (lane >> 3);  // candidate slot (8-lane group id)
  float4 pA[4], pB[4];
#pragma unroll
  for (int r = 0; r < 4; ++r) {
    pA[r] = sp4[(size_t)(tg + r) * N4 + tid];
    pB[r] = sp4[(size_t)(tg + r) * N4 + tid + half];
  }
#pragma unroll
  for (int r = 0; r < 8; ++r) {
    const float4 s  = pA[r & 3];
    const float4 s2 = pB[r & 3];
    if (r < 4) {
      pA[r & 3] = sp4[(size_t)(tg + r + 4) * N4 + tid];
      pB[r & 3] = sp4[(size_t)(tg + r + 4) * N4 + tid + half];
    }

    EMA_ROW(s, s2);

    const float cA0 = __fmul_rn(nmA.x, C_WTA), cA1 = __fmul_rn(nmA.y, C_WTA);
    const float cA2 = __fmul_rn(nmA.z, C_WTA), cA3 = __fmul_rn(nmA.w, C_WTA);
    const float cB0 = __fmul_rn(nmB.x, C_WTA), cB1 = __fmul_rn(nmB.y, C_WTA);
    const float cB2 = __fmul_rn(nmB.z, C_WTA), cB3 = __fmul_rn(nmB.w, C_WTA);
    float mx = fmaxf(fmaxf(fmaxf(nmA.x, nmA.y), fmaxf(nmA.z, nmA.w)),
                     fmaxf(fmaxf(nmB.x, nmB.y), fmaxf(nmB.z, nmB.w)));

    float a1 = cA0; int i1 = baseA;
    float a2 = -__builtin_inff(); int i2 = 0x7fffffff;
    LOCAL_TOP2(cA1, baseA + 1); LOCAL_TOP2(cA2, baseA + 2); LOCAL_TOP2(cA3, baseA + 3);
    LOCAL_TOP2(cB0, baseB);     LOCAL_TOP2(cB1, baseB + 1);
    LOCAL_TOP2(cB2, baseB + 2); LOCAL_TOP2(cB3, baseB + 3);

    // partial butterfly: 3 rounds -> each 8-lane group holds its merged top-2
#pragma unroll
    for (int m = 1; m < 8; m <<= 1) {
      const float b1 = __shfl_xor(a1, m, 64); const int j1 = __shfl_xor(i1, m, 64);
      const float b2 = __shfl_xor(a2, m, 64); const int j2 = __shfl_xor(i2, m, 64);
      mx = fmaxf(mx, __shfl_xor(mx, m, 64));
      merge2(a1, i1, a2, i2, b1, j1, b2, j2);
    }
    if ((lane & 7) == 0) {
      ws1[r][cslot] = a1; wi1s[r][cslot] = i1;
      ws2[r][cslot] = a2; wi2s[r][cslot] = i2;
      wmx[r][cslot] = mx;
    }
  }
  __syncthreads();

  // ---------- pass B: each wave finishes 1 row (64 candidates, 6-round butterfly) ----------
  {
    const int row = wv;
    float a1 = ws1[row][lane]; int i1 = wi1s[row][lane];
    float a2 = ws2[row][lane]; int i2 = wi2s[row][lane];
    float gm = wmx[row][lane];
#pragma unroll
    for (int m = 1; m < 64; m <<= 1) {
      const float b1 = __shfl_xor(a1, m, 64); const int j1 = __shfl_xor(i1, m, 64);
      const float b2 = __shfl_xor(a2, m, 64); const int j2 = __shfl_xor(i2, m, 64);
      gm = fmaxf(gm, __shfl_xor(gm, m, 64));
      merge2(a1, i1, a2, i2, b1, j1, b2, j2);
    }
    if (lane == 0) {
      const int ig = (gm >= C_THR) ? 1 : 0;
      gj1[row] = ig ? i1 : -1;          // -1 sentinel: nothing matches -> zero row
      gj2[row] = ig ? i2 : -1;
      cov[tg + row] = ig ? covval : 0.0f;
    }
  }
  __syncthreads();

  // ---------- pass C: stream out 8 mask rows (nontemporal) ----------
#pragma unroll
  for (int r = 0; r < 8; ++r) {
    const int j1 = gj1[r], j2 = gj2[r];
    f32x4 v, u;
    v.x = (j1 == baseA     || j2 == baseA)     ? 1.0f : 0.0f;
    v.y = (j1 == baseA + 1 || j2 == baseA + 1) ? 1.0f : 0.0f;
    v.z = (j1 == baseA + 2 || j2 == baseA + 2) ? 1.0f : 0.0f;
    v.w = (j1 == baseA + 3 || j2 == baseA + 3) ? 1.0f : 0.0f;
    u.x = (j1 == baseB     || j2 == baseB)     ? 1.0f : 0.0f;
    u.y = (j1 == baseB + 1 || j2 == baseB + 1) ? 1.0f : 0.0f;
    u.z = (j1 == baseB + 2 || j2 == baseB + 2) ? 1.0f : 0.0f;
    u.w = (j1 == baseB + 3 || j2 == baseB + 3) ? 1.0f : 0.0f;
    __builtin_nontemporal_store(v, &mk4[(size_t)(tg + r) * N4 + tid]);
    __builtin_nontemporal_store(u, &mk4[(size_t)(tg + r) * N4 + tid + half]);
  }
}

// ---------------- Phase 2 (generic fallback, R13-proven): GR-row groups over L ----------------
template<int GR>
__global__ __launch_bounds__(512)
void gw_phase2(const float* __restrict__ spikes, const float* __restrict__ bnd,
               float* __restrict__ mask, float* __restrict__ cov,
               int T, int N, int L, float covval) {
  const int tid  = threadIdx.x;
  const int lane = tid & 63;
  const int wv   = tid >> 6;
  const int N4   = N >> 2;
  const int half = N4 >> 1;
  const float4* sp4 = (const float4*)spikes;
  f32x4* mk4 = (f32x4*)mask;

  __shared__ float ws1[GR][64]; __shared__ int wi1s[GR][64];
  __shared__ float ws2[GR][64]; __shared__ int wi2s[GR][64];
  __shared__ float wmx[GR][64];
  __shared__ int gj1[GR], gj2[GR];

  const int chunk = blockIdx.x;
  float4 nmA = ((const float4*)bnd)[(size_t)chunk * N4 + tid];
  float4 nmB = ((const float4*)bnd)[(size_t)chunk * N4 + tid + half];
  const int baseA = tid * 4;
  const int baseB = baseA + (N >> 1);
  const int t00   = chunk * L;
  const int cslot = wv * 8 + (lane >> 3);

  for (int g = 0; g < L; g += GR) {
    const int tg = t00 + g;
    float4 pA[4], pB[4];
#pragma unroll
    for (int r = 0; r < 4; ++r) {
      pA[r] = sp4[(size_t)(tg + r) * N4 + tid];
      pB[r] = sp4[(size_t)(tg + r) * N4 + tid + half];
    }
#pragma unroll
    for (int r = 0; r < GR; ++r) {
      const float4 s  = pA[r & 3];
      const float4 s2 = pB[r & 3];
      if (r < GR - 4) {
        pA[r & 3] = sp4[(size_t)(tg + r + 4) * N4 + tid];
        pB[r & 3] = sp4[(size_t)(tg + r + 4) * N4 + tid + half];
      }
      EMA_ROW(s, s2);
      const float cA0 = __fmul_rn(nmA.x, C_WTA), cA1 = __fmul_rn(nmA.y, C_WTA);
      const float cA2 = __fmul_rn(nmA.z, C_WTA), cA3 = __fmul_rn(nmA.w, C_WTA);
      const float cB0 = __fmul_rn(nmB.x, C_WTA), cB1 = __fmul_rn(nmB.y, C_WTA);
      const float cB2 = __fmul_rn(nmB.z, C_WTA), cB3 = __fmul_rn(nmB.w, C_WTA);
      float mx = fmaxf(fmaxf(fmaxf(nmA.x, nmA.y), fmaxf(nmA.z, nmA.w)),
                       fmaxf(fmaxf(nmB.x, nmB.y), fmaxf(nmB.z, nmB.w)));
      float a1 = cA0; int i1 = baseA;
      float a2 = -__builtin_inff(); int i2 = 0x7fffffff;
      LOCAL_TOP2(cA1, baseA + 1); LOCAL_TOP2(cA2, baseA + 2); LOCAL_TOP2(cA3, baseA + 3);
      LOCAL_TOP2(cB0, baseB);     LOCAL_TOP2(cB1, baseB + 1);
      LOCAL_TOP2(cB2, baseB + 2); LOCAL_TOP2(cB3, baseB + 3);
#pragma unroll
      for (int m = 1; m < 8; m <<= 1) {
        const float b1 = __shfl_xor(a1, m, 64); const int j1 = __shfl_xor(i1, m, 64);
        const float b2 = __shfl_xor(a2, m, 64); const int j2 = __shfl_xor(i2, m, 64);
        mx = fmaxf(mx, __shfl_xor(mx, m, 64));
        merge2(a1, i1, a2, i2, b1, j1, b2, j2);
      }
      if ((lane & 7) == 0) {
        ws1[r][cslot] = a1; wi1s[r][cslot] = i1;
        ws2[r][cslot] = a2; wi2s[r][cslot] = i2;
        wmx[r][cslot] = mx;
      }
    }
    __syncthreads();
#pragma unroll
    for (int rr = 0; rr < GR / 8; ++rr) {
      const int row = wv * (GR / 8) + rr;
      float a1 = ws1[row][lane]; int i1 = wi1s[row][lane];
      float a2 = ws2[row][lane]; int i2 = wi2s[row][lane];
      float gm = wmx[row][lane];
#pragma unroll
      for (int m = 1; m < 64; m <<= 1) {
        const float b1 = __shfl_xor(a1, m, 64); const int j1 = __shfl_xor(i1, m, 64);
        const float b2 = __shfl_xor(a2, m, 64); const int j2 = __shfl_xor(i2, m, 64);
        gm = fmaxf(gm, __shfl_xor(gm, m, 64));
        merge2(a1, i1, a2, i2, b1, j1, b2, j2);
      }
      if (lane == 0) {
        const int ig = (gm >= C_THR) ? 1 : 0;
        gj1[row] = ig ? i1 : -1;
        gj2[row] = ig ? i2 : -1;
        cov[tg + row] = ig ? covval : 0.0f;
      }
    }
    __syncthreads();
#pragma unroll
    for (int r = 0; r < GR; ++r) {
      const int j1 = gj1[r], j2 = gj2[r];
      f32x4 v, u;
      v.x = (j1 == baseA     || j2 == baseA)     ? 1.0f : 0.0f;
      v.y = (j1 == baseA + 1 || j2 == baseA + 1) ? 1.0f : 0.0f;
      v.z = (j1 == baseA + 2 || j2 == baseA + 2) ? 1.0f : 0.0f;
      v.w = (j1 == baseA + 3 || j2 == baseA + 3) ? 1.0f : 0.0f;
      u.x = (j1 == baseB     || j2 == baseB)     ? 1.0f : 0.0f;
      u.y = (j1 == baseB + 1 || j2 == baseB + 1) ? 1.0f : 0.0f;
      u.z = (j1 == baseB + 2 || j2 == baseB + 2) ? 1.0f : 0.0f;
      u.w = (j1 == baseB + 3 || j2 == baseB + 3) ? 1.0f : 0.0f;
      __builtin_nontemporal_store(v, &mk4[(size_t)(tg + r) * N4 + tid]);
      __builtin_nontemporal_store(u, &mk4[(size_t)(tg + r) * N4 + tid + half]);
    }
    if (g + GR < L) __syncthreads();
  }
}

extern "C" void kernel_launch(void* const* d_in, const int* in_sizes, int n_in,
                              void* d_out, int out_size, void* d_ws, size_t ws_size,
                              hipStream_t stream) {
  const float* spikes = (const float*)d_in[0];
  const float* nmda0  = (const float*)d_in[1];
  const int N = in_sizes[1];
  const int T = in_sizes[0] / N;

  float* out  = (float*)d_out;
  float* mask = out;                               // [T, N]
  float* cov  = out + (size_t)T * N;               // [T]
  float* nmf  = cov + T;                           // [N]

  // boundary-state chunk length L = 1<<Ls; Ls=4 (phase1-optimal), shrink if ws is small
  int Ls = 4;
  while (((size_t)(T >> Ls)) * (size_t)N * sizeof(float) > ws_size && Ls < 13) ++Ls;
  const int L = 1 << Ls;
  const int C = T >> Ls;
  float* bnd = (float*)d_ws;                       // [C, N]
  const float covval = 2.0f / (float)N;

  gw_phase1<<<N / NPB, 128, 0, stream>>>(spikes, nmda0, bnd, nmf, T, N, Ls);
  if (L == 16)
    gw_phase2s<<<2 * C, 512, 0, stream>>>(spikes, bnd, mask, cov, T, N, covval);
  else if (L % 8 == 0)
    gw_phase2<8><<<C, 512, 0, stream>>>(spikes, bnd, mask, cov, T, N, L, covval);
  else
    gw_phase2<16><<<C, 512, 0, stream>>>(spikes, bnd, mask, cov, T, N, L, covval);
}

// Round 18
// 115.963 us; speedup vs baseline: 1.0826x; 1.0547x over previous
//
#include <hip/hip_runtime.h>
#include <cstdint>
#include <cstddef>

// ---- constants from the reference config (exact fp32 images of the Python doubles) ----
#define C_DECAY 0.99f   // (1.0 - alpha), alpha = 1.0/100.0
#define C_ALPHA 0.01f   // alpha
#define C_THR   0.58f   // IGNITE_THR
#define C_WTA   0.85f   // WTA_INH

#define NPB   16        // neurons per phase1 block (64B per spike row slice)
#define TILE  256       // timesteps per LDS tile (phase1); 16 KiB per buffer

// EMA step: EXACT replica of the reference op order. DO NOT rewrite algebraically
// (R10 lesson: fmaf substitution broke bitwise equality despite a paper proof).
#define EMA_STEP(x) nmda = __fadd_rn(__fmul_rn(C_DECAY, nmda), __fmul_rn(C_ALPHA, (x)))

typedef const __attribute__((address_space(1))) void g_void;
typedef __attribute__((address_space(3))) void l_void;
typedef float f32x4 __attribute__((ext_vector_type(4)));

// async global->LDS DMA, 16B/lane, wave-uniform LDS base (lane i lands at base + i*16)
__device__ __forceinline__ void gload_lds16(const float* g, float* l) {
  __builtin_amdgcn_global_load_lds((g_void*)g, (l_void*)l, 16, 0, 0);
}

// ---------------- Phase 1: R11 body + register-bank capture of mid-chunk states ----------------
// grid: N/16 = 256 blocks; block: 128 threads (wave0 = compute, wave1 = async loader)
// [R13/R14/R16 lesson: NO extra stores inside the jp loop. Mid states -> regs (1 v_mov each),
//  flushed to bndh ONCE per tile right before the barrier where the wave stalls anyway.]
__global__ __launch_bounds__(128)
void gw_phase1(const float* __restrict__ spikes, const float* __restrict__ nmda0,
               float* __restrict__ bnd, float* __restrict__ bndh,
               float* __restrict__ nmf, int T, int N, int Ls) {
  __shared__ float sb[2][TILE * NPB];   // 2 x 16 KiB, linear [step][neuron]
  const int w    = threadIdx.x >> 6;
  const int lane = threadIdx.x & 63;
  const int nblk = gridDim.x;                       // N/NPB
  const int bs   = (nblk % 8 == 0) ? ((blockIdx.x & 7) * (nblk >> 3) + (blockIdx.x >> 3))
                                   : (int)blockIdx.x;
  const int n0   = bs * NPB;
  const int ntiles = T / TILE;
  const int Lm1  = (1 << Ls) - 1;
  const int grow = lane >> 2;        // row within a 16-row DMA group
  const int gc   = (lane & 3) * 4;   // float column within the 16-float row

  if (w == 1) {   // prologue: stage tile 0 (16 x 1KiB async DMAs)
#pragma unroll
    for (int j = 0; j < TILE / 16; ++j)
      gload_lds16(spikes + (size_t)(j * 16 + grow) * N + n0 + gc, &sb[0][j * 256]);
  }
  __syncthreads();   // drains vmcnt -> tile 0 resident

  const int nn = lane & (NPB - 1);   // 4 lanes duplicate each neuron (broadcast reads)
  float nmda = 0.0f;
  if (w == 0) nmda = nmda0[n0 + nn];

  for (int tile = 0; tile < ntiles; ++tile) {
    const int cur = tile & 1;
    if (w == 0) {
      const float* buf = sb[cur];
      const int t0 = tile * TILE;
      float tA[16], tB[16], sv[16];
#pragma unroll
      for (int i = 0; i < 16; ++i) tA[i] = buf[i * NPB + nn];
#pragma unroll
      for (int jp = 0; jp < TILE / 32; ++jp) {
        // even group: consume tA, prefetch odd group into tB
#pragma unroll
        for (int i = 0; i < 16; ++i) tB[i] = buf[((2 * jp + 1) * 16 + i) * NPB + nn];
        { const int tb = t0 + 2 * jp * 16;
          if ((tb & Lm1) == 0 && lane < NPB) bnd[(size_t)(tb >> Ls) * N + n0 + lane] = nmda; }
#pragma unroll
        for (int i = 0; i < 8; ++i) EMA_STEP(tA[i]);
        sv[2 * jp] = nmda;                 // state before step t0+2jp*16+8 (off-chain v_mov)
#pragma unroll
        for (int i = 8; i < 16; ++i) EMA_STEP(tA[i]);
        // odd group: consume tB, prefetch next even group into tA
        if (jp < TILE / 32 - 1) {
#pragma unroll
          for (int i = 0; i < 16; ++i) tA[i] = buf[((2 * jp + 2) * 16 + i) * NPB + nn];
        }
        { const int tb = t0 + (2 * jp + 1) * 16;
          if ((tb & Lm1) == 0 && lane < NPB) bnd[(size_t)(tb >> Ls) * N + n0 + lane] = nmda; }
#pragma unroll
        for (int i = 0; i < 8; ++i) EMA_STEP(tB[i]);
        sv[2 * jp + 1] = nmda;             // state before step t0+(2jp+1)*16+8
#pragma unroll
        for (int i = 8; i < 16; ++i) EMA_STEP(tB[i]);
      }
      // deferred flush of the 16 mid-chunk states (overlaps the tile-end barrier wait)
      if (bndh != nullptr && lane < NPB) {
#pragma unroll
        for (int g2 = 0; g2 < 16; ++g2)
          bndh[(size_t)(t0 / 16 + g2) * N + n0 + lane] = sv[g2];
      }
    } else if (tile + 1 < ntiles) {
      const int t0 = (tile + 1) * TILE;
#pragma unroll
      for (int j = 0; j < TILE / 16; ++j)
        gload_lds16(spikes + (size_t)(t0 + j * 16 + grow) * N + n0 + gc, &sb[cur ^ 1][j * 256]);
    }
    __syncthreads();
  }
  if (w == 0 && lane < NPB) nmf[n0 + lane] = nmda;
}

// lexicographic merge of two (score desc, index asc) top-2 tuples
__device__ __forceinline__ void merge2(float& a1, int& i1, float& a2, int& i2,
                                       float b1, int j1, float b2, int j2) {
  const bool afirst = (a1 > b1) || (a1 == b1 && i1 < j1);
  const float w1 = afirst ? a1 : b1; const int wi1 = afirst ? i1 : j1;
  const float l1 = afirst ? b1 : a1; const int li1 = afirst ? j1 : i1;
  const float cc = afirst ? a2 : b2; const int ci  = afirst ? i2 : j2;
  const bool sfirst = (cc > l1) || (cc == l1 && ci < li1);
  a1 = w1; i1 = wi1;
  a2 = sfirst ? cc : l1; i2 = sfirst ? ci : li1;
}

// local stable top-2 update with a new (score, idx), idx processed in ascending order
#define LOCAL_TOP2(c, idx)                                         \
  if ((c) > a1) { a2 = a1; i2 = i1; a1 = (c); i1 = (idx); }        \
  else if ((c) > a2) { a2 = (c); i2 = (idx); }

// exact EMA update of both float4 segments (reference op order)
#define EMA_ROW(sA, sB)                                                        \
  nmA.x = __fadd_rn(__fmul_rn(C_DECAY, nmA.x), __fmul_rn(C_ALPHA, (sA).x));    \
  nmA.y = __fadd_rn(__fmul_rn(C_DECAY, nmA.y), __fmul_rn(C_ALPHA, (sA).y));    \
  nmA.z = __fadd_rn(__fmul_rn(C_DECAY, nmA.z), __fmul_rn(C_ALPHA, (sA).z));    \
  nmA.w = __fadd_rn(__fmul_rn(C_DECAY, nmA.w), __fmul_rn(C_ALPHA, (sA).w));    \
  nmB.x = __fadd_rn(__fmul_rn(C_DECAY, nmB.x), __fmul_rn(C_ALPHA, (sB).x));    \
  nmB.y = __fadd_rn(__fmul_rn(C_DECAY, nmB.y), __fmul_rn(C_ALPHA, (sB).y));    \
  nmB.z = __fadd_rn(__fmul_rn(C_DECAY, nmB.z), __fmul_rn(C_ALPHA, (sB).z));    \
  nmB.w = __fadd_rn(__fmul_rn(C_DECAY, nmB.w), __fmul_rn(C_ALPHA, (sB).w));

// ---------------- Phase 2 (parity): 1024 blocks x 8 rows; state from bnd/bndh by parity ----------------
// [R16-proven body @1024 blocks: 33.5us] grid: T/8 blocks; block: 512 threads (8 waves).
__global__ __launch_bounds__(512)
void gw_phase2p(const float* __restrict__ spikes, const float* __restrict__ bnd,
                const float* __restrict__ bndh,
                float* __restrict__ mask, float* __restrict__ cov,
                int T, int N, float covval) {
  const int tid  = threadIdx.x;            // [0, 512)
  const int lane = tid & 63;
  const int wv   = tid >> 6;               // wave id [0,8)
  const int N4   = N >> 2;
  const int half = N4 >> 1;
  const float4* sp4 = (const float4*)spikes;
  f32x4* mk4 = (f32x4*)mask;

  __shared__ float ws1[8][64]; __shared__ int wi1s[8][64];
  __shared__ float ws2[8][64]; __shared__ int wi2s[8][64];
  __shared__ float wmx[8][64];
  __shared__ int gj1[8], gj2[8];

  const int chunk = blockIdx.x;            // 8-step chunk id [0, T/8)
  const int k     = chunk >> 1;
  const float4* src = (chunk & 1) ? (const float4*)bndh : (const float4*)bnd;
  float4 nmA = src[(size_t)k * N4 + tid];
  float4 nmB = src[(size_t)k * N4 + tid + half];
  const int baseA = tid * 4;
  const int baseB = baseA + (N >> 1);
  const int tg    = chunk * 8;
  const int cslot = wv * 8 + (lane >> 3);  // candidate slot (8-lane group id)

  // ---------- pass A: 8 rows, depth-4 ring prefetch, 3-round partial butterfly ----------
  float4 pA[4], pB[4];
#pragma unroll
  for (int r = 0; r < 4; ++r) {
    pA[r] = sp4[(size_t)(tg + r) * N4 + tid];
    pB[r] = sp4[(size_t)(tg + r) * N4 + tid + half];
  }
#pragma unroll
  for (int r = 0; r < 8; ++r) {
    const float4 s  = pA[r & 3];
    const float4 s2 = pB[r & 3];
    if (r < 4) {
      pA[r & 3] = sp4[(size_t)(tg + r + 4) * N4 + tid];
      pB[r & 3] = sp4[(size_t)(tg + r + 4) * N4 + tid + half];
    }

    EMA_ROW(s, s2);

    const float cA0 = __fmul_rn(nmA.x, C_WTA), cA1 = __fmul_rn(nmA.y, C_WTA);
    const float cA2 = __fmul_rn(nmA.z, C_WTA), cA3 = __fmul_rn(nmA.w, C_WTA);
    const float cB0 = __fmul_rn(nmB.x, C_WTA), cB1 = __fmul_rn(nmB.y, C_WTA);
    const float cB2 = __fmul_rn(nmB.z, C_WTA), cB3 = __fmul_rn(nmB.w, C_WTA);
    float mx = fmaxf(fmaxf(fmaxf(nmA.x, nmA.y), fmaxf(nmA.z, nmA.w)),
                     fmaxf(fmaxf(nmB.x, nmB.y), fmaxf(nmB.z, nmB.w)));

    float a1 = cA0; int i1 = baseA;
    float a2 = -__builtin_inff(); int i2 = 0x7fffffff;
    LOCAL_TOP2(cA1, baseA + 1); LOCAL_TOP2(cA2, baseA + 2); LOCAL_TOP2(cA3, baseA + 3);
    LOCAL_TOP2(cB0, baseB);     LOCAL_TOP2(cB1, baseB + 1);
    LOCAL_TOP2(cB2, baseB + 2); LOCAL_TOP2(cB3, baseB + 3);

    // partial butterfly: 3 rounds -> each 8-lane group holds its merged top-2
#pragma unroll
    for (int m = 1; m < 8; m <<= 1) {
      const float b1 = __shfl_xor(a1, m, 64); const int j1 = __shfl_xor(i1, m, 64);
      const float b2 = __shfl_xor(a2, m, 64); const int j2 = __shfl_xor(i2, m, 64);
      mx = fmaxf(mx, __shfl_xor(mx, m, 64));
      merge2(a1, i1, a2, i2, b1, j1, b2, j2);
    }
    if ((lane & 7) == 0) {
      ws1[r][cslot] = a1; wi1s[r][cslot] = i1;
      ws2[r][cslot] = a2; wi2s[r][cslot] = i2;
      wmx[r][cslot] = mx;
    }
  }
  __syncthreads();

  // ---------- pass B: each wave finishes 1 row (64 candidates, 6-round butterfly) ----------
  {
    const int row = wv;
    float a1 = ws1[row][lane]; int i1 = wi1s[row][lane];
    float a2 = ws2[row][lane]; int i2 = wi2s[row][lane];
    float gm = wmx[row][lane];
#pragma unroll
    for (int m = 1; m < 64; m <<= 1) {
      const float b1 = __shfl_xor(a1, m, 64); const int j1 = __shfl_xor(i1, m, 64);
      const float b2 = __shfl_xor(a2, m, 64); const int j2 = __shfl_xor(i2, m, 64);
      gm = fmaxf(gm, __shfl_xor(gm, m, 64));
      merge2(a1, i1, a2, i2, b1, j1, b2, j2);
    }
    if (lane == 0) {
      const int ig = (gm >= C_THR) ? 1 : 0;
      gj1[row] = ig ? i1 : -1;          // -1 sentinel: nothing matches -> zero row
      gj2[row] = ig ? i2 : -1;
      cov[tg + row] = ig ? covval : 0.0f;
    }
  }
  __syncthreads();

  // ---------- pass C: stream out 8 mask rows (nontemporal) ----------
#pragma unroll
  for (int r = 0; r < 8; ++r) {
    const int j1 = gj1[r], j2 = gj2[r];
    f32x4 v, u;
    v.x = (j1 == baseA     || j2 == baseA)     ? 1.0f : 0.0f;
    v.y = (j1 == baseA + 1 || j2 == baseA + 1) ? 1.0f : 0.0f;
    v.z = (j1 == baseA + 2 || j2 == baseA + 2) ? 1.0f : 0.0f;
    v.w = (j1 == baseA + 3 || j2 == baseA + 3) ? 1.0f : 0.0f;
    u.x = (j1 == baseB     || j2 == baseB)     ? 1.0f : 0.0f;
    u.y = (j1 == baseB + 1 || j2 == baseB + 1) ? 1.0f : 0.0f;
    u.z = (j1 == baseB + 2 || j2 == baseB + 2) ? 1.0f : 0.0f;
    u.w = (j1 == baseB + 3 || j2 == baseB + 3) ? 1.0f : 0.0f;
    __builtin_nontemporal_store(v, &mk4[(size_t)(tg + r) * N4 + tid]);
    __builtin_nontemporal_store(u, &mk4[(size_t)(tg + r) * N4 + tid + half]);
  }
}

// ---------------- Phase 2 (generic fallback, R13-proven): GR-row groups over L ----------------
template<int GR>
__global__ __launch_bounds__(512)
void gw_phase2(const float* __restrict__ spikes, const float* __restrict__ bnd,
               float* __restrict__ mask, float* __restrict__ cov,
               int T, int N, int L, float covval) {
  const int tid  = threadIdx.x;
  const int lane = tid & 63;
  const int wv   = tid >> 6;
  const int N4   = N >> 2;
  const int half = N4 >> 1;
  const float4* sp4 = (const float4*)spikes;
  f32x4* mk4 = (f32x4*)mask;

  __shared__ float ws1[GR][64]; __shared__ int wi1s[GR][64];
  __shared__ float ws2[GR][64]; __shared__ int wi2s[GR][64];
  __shared__ float wmx[GR][64];
  __shared__ int gj1[GR], gj2[GR];

  const int chunk = blockIdx.x;
  float4 nmA = ((const float4*)bnd)[(size_t)chunk * N4 + tid];
  float4 nmB = ((const float4*)bnd)[(size_t)chunk * N4 + tid + half];
  const int baseA = tid * 4;
  const int baseB = baseA + (N >> 1);
  const int t00   = chunk * L;
  const int cslot = wv * 8 + (lane >> 3);

  for (int g = 0; g < L; g += GR) {
    const int tg = t00 + g;
    float4 pA[4], pB[4];
#pragma unroll
    for (int r = 0; r < 4; ++r) {
      pA[r] = sp4[(size_t)(tg + r) * N4 + tid];
      pB[r] = sp4[(size_t)(tg + r) * N4 + tid + half];
    }
#pragma unroll
    for (int r = 0; r < GR; ++r) {
      const float4 s  = pA[r & 3];
      const float4 s2 = pB[r & 3];
      if (r < GR - 4) {
        pA[r & 3] = sp4[(size_t)(tg + r + 4) * N4 + tid];
        pB[r & 3] = sp4[(size_t)(tg + r + 4) * N4 + tid + half];
      }
      EMA_ROW(s, s2);
      const float cA0 = __fmul_rn(nmA.x, C_WTA), cA1 = __fmul_rn(nmA.y, C_WTA);
      const float cA2 = __fmul_rn(nmA.z, C_WTA), cA3 = __fmul_rn(nmA.w, C_WTA);
      const float cB0 = __fmul_rn(nmB.x, C_WTA), cB1 = __fmul_rn(nmB.y, C_WTA);
      const float cB2 = __fmul_rn(nmB.z, C_WTA), cB3 = __fmul_rn(nmB.w, C_WTA);
      float mx = fmaxf(fmaxf(fmaxf(nmA.x, nmA.y), fmaxf(nmA.z, nmA.w)),
                       fmaxf(fmaxf(nmB.x, nmB.y), fmaxf(nmB.z, nmB.w)));
      float a1 = cA0; int i1 = baseA;
      float a2 = -__builtin_inff(); int i2 = 0x7fffffff;
      LOCAL_TOP2(cA1, baseA + 1); LOCAL_TOP2(cA2, baseA + 2); LOCAL_TOP2(cA3, baseA + 3);
      LOCAL_TOP2(cB0, baseB);     LOCAL_TOP2(cB1, baseB + 1);
      LOCAL_TOP2(cB2, baseB + 2); LOCAL_TOP2(cB3, baseB + 3);
#pragma unroll
      for (int m = 1; m < 8; m <<= 1) {
        const float b1 = __shfl_xor(a1, m, 64); const int j1 = __shfl_xor(i1, m, 64);
        const float b2 = __shfl_xor(a2, m, 64); const int j2 = __shfl_xor(i2, m, 64);
        mx = fmaxf(mx, __shfl_xor(mx, m, 64));
        merge2(a1, i1, a2, i2, b1, j1, b2, j2);
      }
      if ((lane & 7) == 0) {
        ws1[r][cslot] = a1; wi1s[r][cslot] = i1;
        ws2[r][cslot] = a2; wi2s[r][cslot] = i2;
        wmx[r][cslot] = mx;
      }
    }
    __syncthreads();
#pragma unroll
    for (int rr = 0; rr < GR / 8; ++rr) {
      const int row = wv * (GR / 8) + rr;
      float a1 = ws1[row][lane]; int i1 = wi1s[row][lane];
      float a2 = ws2[row][lane]; int i2 = wi2s[row][lane];
      float gm = wmx[row][lane];
#pragma unroll
      for (int m = 1; m < 64; m <<= 1) {
        const float b1 = __shfl_xor(a1, m, 64); const int j1 = __shfl_xor(i1, m, 64);
        const float b2 = __shfl_xor(a2, m, 64); const int j2 = __shfl_xor(i2, m, 64);
        gm = fmaxf(gm, __shfl_xor(gm, m, 64));
        merge2(a1, i1, a2, i2, b1, j1, b2, j2);
      }
      if (lane == 0) {
        const int ig = (gm >= C_THR) ? 1 : 0;
        gj1[row] = ig ? i1 : -1;
        gj2[row] = ig ? i2 : -1;
        cov[tg + row] = ig ? covval : 0.0f;
      }
    }
    __syncthreads();
#pragma unroll
    for (int r = 0; r < GR; ++r) {
      const int j1 = gj1[r], j2 = gj2[r];
      f32x4 v, u;
      v.x = (j1 == baseA     || j2 == baseA)     ? 1.0f : 0.0f;
      v.y = (j1 == baseA + 1 || j2 == baseA + 1) ? 1.0f : 0.0f;
      v.z = (j1 == baseA + 2 || j2 == baseA + 2) ? 1.0f : 0.0f;
      v.w = (j1 == baseA + 3 || j2 == baseA + 3) ? 1.0f : 0.0f;
      u.x = (j1 == baseB     || j2 == baseB)     ? 1.0f : 0.0f;
      u.y = (j1 == baseB + 1 || j2 == baseB + 1) ? 1.0f : 0.0f;
      u.z = (j1 == baseB + 2 || j2 == baseB + 2) ? 1.0f : 0.0f;
      u.w = (j1 == baseB + 3 || j2 == baseB + 3) ? 1.0f : 0.0f;
      __builtin_nontemporal_store(v, &mk4[(size_t)(tg + r) * N4 + tid]);
      __builtin_nontemporal_store(u, &mk4[(size_t)(tg + r) * N4 + tid + half]);
    }
    if (g + GR < L) __syncthreads();
  }
}

extern "C" void kernel_launch(void* const* d_in, const int* in_sizes, int n_in,
                              void* d_out, int out_size, void* d_ws, size_t ws_size,
                              hipStream_t stream) {
  const float* spikes = (const float*)d_in[0];
  const float* nmda0  = (const float*)d_in[1];
  const int N = in_sizes[1];
  const int T = in_sizes[0] / N;

  float* out  = (float*)d_out;
  float* mask = out;                               // [T, N]
  float* cov  = out + (size_t)T * N;               // [T]
  float* nmf  = cov + T;                           // [N]
  const float covval = 2.0f / (float)N;

  // split path: bnd (Ls=4 chunks) + bndh (mid-chunk states) -> 1024-block phase2
  const int C16 = T >> 4;
  const size_t need2 = 2 * (size_t)C16 * N * sizeof(float);
  const bool split = (T % (2 * TILE) == 0) && (need2 <= ws_size);

  if (split) {
    float* bnd  = (float*)d_ws;                    // [C16, N] states before 16k
    float* bndh = bnd + (size_t)C16 * N;           // [C16, N] states before 16k+8
    gw_phase1<<<N / NPB, 128, 0, stream>>>(spikes, nmda0, bnd, bndh, nmf, T, N, 4);
    gw_phase2p<<<T / 8, 512, 0, stream>>>(spikes, bnd, bndh, mask, cov, T, N, covval);
  } else {
    int Ls = 4;
    while (((size_t)(T >> Ls)) * (size_t)N * sizeof(float) > ws_size && Ls < 13) ++Ls;
    const int L = 1 << Ls;
    const int C = T >> Ls;
    float* bnd = (float*)d_ws;
    gw_phase1<<<N / NPB, 128, 0, stream>>>(spikes, nmda0, bnd, nullptr, nmf, T, N, Ls);
    if (L % 8 == 0 && L % 16 != 0)
      gw_phase2<8><<<C, 512, 0, stream>>>(spikes, bnd, mask, cov, T, N, L, covval);
    else
      gw_phase2<16><<<C, 512, 0, stream>>>(spikes, bnd, mask, cov, T, N, L, covval);
  }
}

// Round 19
// 114.396 us; speedup vs baseline: 1.0974x; 1.0137x over previous
//
#include <hip/hip_runtime.h>
#include <cstdint>
#include <cstddef>

// ---- constants from the reference config (exact fp32 images of the Python doubles) ----
#define C_DECAY 0.99f   // (1.0 - alpha), alpha = 1.0/100.0
#define C_ALPHA 0.01f   // alpha
#define C_THR   0.58f   // IGNITE_THR
#define C_WTA   0.85f   // WTA_INH

#define NPB   16        // neurons per phase1 block (64B per spike row slice)
#define TILE  256       // timesteps per LDS tile (phase1); 16 KiB per buffer

// EMA step: EXACT replica of the reference op order. DO NOT rewrite algebraically
// (R10 lesson: fmaf substitution broke bitwise equality despite a paper proof).
#define EMA_STEP(x) nmda = __fadd_rn(__fmul_rn(C_DECAY, nmda), __fmul_rn(C_ALPHA, (x)))

typedef const __attribute__((address_space(1))) void g_void;
typedef __attribute__((address_space(3))) void l_void;
typedef float f32x4 __attribute__((ext_vector_type(4)));

// async global->LDS DMA, 16B/lane, wave-uniform LDS base (lane i lands at base + i*16)
__device__ __forceinline__ void gload_lds16(const float* g, float* l) {
  __builtin_amdgcn_global_load_lds((g_void*)g, (l_void*)l, 16, 0, 0);
}

// ---------------- Phase 1: [R11-verbatim, proven ~60us @ Ls=4 — DO NOT TOUCH] ----------------
// grid: N/16 = 256 blocks; block: 128 threads (wave0 = compute, wave1 = async loader)
// [R13/R14/R16/R18: four attempts to add mid-chunk output all cost 18-32us. Local optimum.]
__global__ __launch_bounds__(128)
void gw_phase1(const float* __restrict__ spikes, const float* __restrict__ nmda0,
               float* __restrict__ bnd, float* __restrict__ nmf,
               int T, int N, int Ls) {
  __shared__ float sb[2][TILE * NPB];   // 2 x 16 KiB, linear [step][neuron]
  const int w    = threadIdx.x >> 6;
  const int lane = threadIdx.x & 63;
  const int nblk = gridDim.x;                       // N/NPB
  const int bs   = (nblk % 8 == 0) ? ((blockIdx.x & 7) * (nblk >> 3) + (blockIdx.x >> 3))
                                   : (int)blockIdx.x;
  const int n0   = bs * NPB;
  const int ntiles = T / TILE;
  const int Lm1  = (1 << Ls) - 1;
  const int grow = lane >> 2;        // row within a 16-row DMA group
  const int gc   = (lane & 3) * 4;   // float column within the 16-float row

  if (w == 1) {   // prologue: stage tile 0 (16 x 1KiB async DMAs)
#pragma unroll
    for (int j = 0; j < TILE / 16; ++j)
      gload_lds16(spikes + (size_t)(j * 16 + grow) * N + n0 + gc, &sb[0][j * 256]);
  }
  __syncthreads();   // drains vmcnt -> tile 0 resident

  const int nn = lane & (NPB - 1);   // 4 lanes duplicate each neuron (broadcast reads)
  float nmda = 0.0f;
  if (w == 0) nmda = nmda0[n0 + nn];

  for (int tile = 0; tile < ntiles; ++tile) {
    const int cur = tile & 1;
    if (w == 0) {
      const float* buf = sb[cur];
      const int t0 = tile * TILE;
      float tA[16], tB[16];
#pragma unroll
      for (int i = 0; i < 16; ++i) tA[i] = buf[i * NPB + nn];
#pragma unroll
      for (int jp = 0; jp < TILE / 32; ++jp) {
        // even group: consume tA, prefetch odd group into tB
#pragma unroll
        for (int i = 0; i < 16; ++i) tB[i] = buf[((2 * jp + 1) * 16 + i) * NPB + nn];
        { const int tb = t0 + 2 * jp * 16;
          if ((tb & Lm1) == 0 && lane < NPB) bnd[(size_t)(tb >> Ls) * N + n0 + lane] = nmda; }
#pragma unroll
        for (int i = 0; i < 16; ++i) EMA_STEP(tA[i]);
        // odd group: consume tB, prefetch next even group into tA
        if (jp < TILE / 32 - 1) {
#pragma unroll
          for (int i = 0; i < 16; ++i) tA[i] = buf[((2 * jp + 2) * 16 + i) * NPB + nn];
        }
        { const int tb = t0 + (2 * jp + 1) * 16;
          if ((tb & Lm1) == 0 && lane < NPB) bnd[(size_t)(tb >> Ls) * N + n0 + lane] = nmda; }
#pragma unroll
        for (int i = 0; i < 16; ++i) EMA_STEP(tB[i]);
      }
    } else if (tile + 1 < ntiles) {
      const int t0 = (tile + 1) * TILE;
#pragma unroll
      for (int j = 0; j < TILE / 16; ++j)
        gload_lds16(spikes + (size_t)(t0 + j * 16 + grow) * N + n0 + gc, &sb[cur ^ 1][j * 256]);
    }
    __syncthreads();
  }
  if (w == 0 && lane < NPB) nmf[n0 + lane] = nmda;
}

// lexicographic merge of two (score desc, index asc) top-2 tuples
__device__ __forceinline__ void merge2(float& a1, int& i1, float& a2, int& i2,
                                       float b1, int j1, float b2, int j2) {
  const bool afirst = (a1 > b1) || (a1 == b1 && i1 < j1);
  const float w1 = afirst ? a1 : b1; const int wi1 = afirst ? i1 : j1;
  const float l1 = afirst ? b1 : a1; const int li1 = afirst ? j1 : i1;
  const float cc = afirst ? a2 : b2; const int ci  = afirst ? i2 : j2;
  const bool sfirst = (cc > l1) || (cc == l1 && ci < li1);
  a1 = w1; i1 = wi1;
  a2 = sfirst ? cc : l1; i2 = sfirst ? ci : li1;
}

// local stable top-2 update with a new (score, idx), idx processed in ascending order
#define LOCAL_TOP2(c, idx)                                         \
  if ((c) > a1) { a2 = a1; i2 = i1; a1 = (c); i1 = (idx); }        \
  else if ((c) > a2) { a2 = (c); i2 = (idx); }

// exact EMA update of both float4 segments (reference op order)
#define EMA_ROW(sA, sB)                                                        \
  nmA.x = __fadd_rn(__fmul_rn(C_DECAY, nmA.x), __fmul_rn(C_ALPHA, (sA).x));    \
  nmA.y = __fadd_rn(__fmul_rn(C_DECAY, nmA.y), __fmul_rn(C_ALPHA, (sA).y));    \
  nmA.z = __fadd_rn(__fmul_rn(C_DECAY, nmA.z), __fmul_rn(C_ALPHA, (sA).z));    \
  nmA.w = __fadd_rn(__fmul_rn(C_DECAY, nmA.w), __fmul_rn(C_ALPHA, (sA).w));    \
  nmB.x = __fadd_rn(__fmul_rn(C_DECAY, nmB.x), __fmul_rn(C_ALPHA, (sB).x));    \
  nmB.y = __fadd_rn(__fmul_rn(C_DECAY, nmB.y), __fmul_rn(C_ALPHA, (sB).y));    \
  nmB.z = __fadd_rn(__fmul_rn(C_DECAY, nmB.z), __fmul_rn(C_ALPHA, (sB).z));    \
  nmB.w = __fadd_rn(__fmul_rn(C_DECAY, nmB.w), __fmul_rn(C_ALPHA, (sB).w));

// per-row body: EMA + scores + local top-2 + 3-round butterfly + LDS candidate store
#define P2_ROW_BODY(sA, sB, rr_)                                               \
  {                                                                            \
    EMA_ROW(sA, sB);                                                           \
    const float cA0 = __fmul_rn(nmA.x, C_WTA), cA1 = __fmul_rn(nmA.y, C_WTA);  \
    const float cA2 = __fmul_rn(nmA.z, C_WTA), cA3 = __fmul_rn(nmA.w, C_WTA);  \
    const float cB0 = __fmul_rn(nmB.x, C_WTA), cB1 = __fmul_rn(nmB.y, C_WTA);  \
    const float cB2 = __fmul_rn(nmB.z, C_WTA), cB3 = __fmul_rn(nmB.w, C_WTA);  \
    float mx = fmaxf(fmaxf(fmaxf(nmA.x, nmA.y), fmaxf(nmA.z, nmA.w)),          \
                     fmaxf(fmaxf(nmB.x, nmB.y), fmaxf(nmB.z, nmB.w)));         \
    float a1 = cA0; int i1 = baseA;                                            \
    float a2 = -__builtin_inff(); int i2 = 0x7fffffff;                         \
    LOCAL_TOP2(cA1, baseA + 1); LOCAL_TOP2(cA2, baseA + 2);                    \
    LOCAL_TOP2(cA3, baseA + 3);                                                \
    LOCAL_TOP2(cB0, baseB);     LOCAL_TOP2(cB1, baseB + 1);                    \
    LOCAL_TOP2(cB2, baseB + 2); LOCAL_TOP2(cB3, baseB + 3);                    \
    _Pragma("unroll")                                                          \
    for (int m = 1; m < 8; m <<= 1) {                                          \
      const float b1 = __shfl_xor(a1, m, 64); const int j1 = __shfl_xor(i1, m, 64); \
      const float b2 = __shfl_xor(a2, m, 64); const int j2 = __shfl_xor(i2, m, 64); \
      mx = fmaxf(mx, __shfl_xor(mx, m, 64));                                   \
      merge2(a1, i1, a2, i2, b1, j1, b2, j2);                                  \
    }                                                                          \
    if ((lane & 7) == 0) {                                                     \
      ws1[rr_][cslot] = a1; wi1s[rr_][cslot] = i1;                             \
      ws2[rr_][cslot] = a2; wi2s[rr_][cslot] = i2;                             \
      wmx[rr_][cslot] = mx;                                                    \
    }                                                                          \
  }

// pass B (1 row per wave) + pass C (8 rows out), for rows [tg, tg+8)
#define P2_TAIL(tg)                                                            \
  {                                                                            \
    const int row = wv;                                                        \
    float a1 = ws1[row][lane]; int i1 = wi1s[row][lane];                       \
    float a2 = ws2[row][lane]; int i2 = wi2s[row][lane];                       \
    float gm = wmx[row][lane];                                                 \
    _Pragma("unroll")                                                          \
    for (int m = 1; m < 64; m <<= 1) {                                         \
      const float b1 = __shfl_xor(a1, m, 64); const int j1 = __shfl_xor(i1, m, 64); \
      const float b2 = __shfl_xor(a2, m, 64); const int j2 = __shfl_xor(i2, m, 64); \
      gm = fmaxf(gm, __shfl_xor(gm, m, 64));                                   \
      merge2(a1, i1, a2, i2, b1, j1, b2, j2);                                  \
    }                                                                          \
    if (lane == 0) {                                                           \
      const int ig = (gm >= C_THR) ? 1 : 0;                                    \
      gj1[row] = ig ? i1 : -1;                                                 \
      gj2[row] = ig ? i2 : -1;                                                 \
      cov[(tg) + row] = ig ? covval : 0.0f;                                    \
    }                                                                          \
  }                                                                            \
  __syncthreads();                                                             \
  _Pragma("unroll")                                                            \
  for (int r = 0; r < 8; ++r) {                                                \
    const int j1 = gj1[r], j2 = gj2[r];                                        \
    f32x4 v, u;                                                                \
    v.x = (j1 == baseA     || j2 == baseA)     ? 1.0f : 0.0f;                  \
    v.y = (j1 == baseA + 1 || j2 == baseA + 1) ? 1.0f : 0.0f;                  \
    v.z = (j1 == baseA + 2 || j2 == baseA + 2) ? 1.0f : 0.0f;                  \
    v.w = (j1 == baseA + 3 || j2 == baseA + 3) ? 1.0f : 0.0f;                  \
    u.x = (j1 == baseB     || j2 == baseB)     ? 1.0f : 0.0f;                  \
    u.y = (j1 == baseB + 1 || j2 == baseB + 1) ? 1.0f : 0.0f;                  \
    u.z = (j1 == baseB + 2 || j2 == baseB + 2) ? 1.0f : 0.0f;                  \
    u.w = (j1 == baseB + 3 || j2 == baseB + 3) ? 1.0f : 0.0f;                  \
    __builtin_nontemporal_store(v, &mk4[(size_t)((tg) + r) * N4 + tid]);       \
    __builtin_nontemporal_store(u, &mk4[(size_t)((tg) + r) * N4 + tid + half]); \
  }

// ---------------- Phase 2 (L=16, hoisted cross-group prefetch) ----------------
// 512 blocks x 512 threads; two 8-row groups; group 1's ring-init loads issued during
// group 0's pass A (rows 4-7) so they cross the barriers already in flight.
__global__ __launch_bounds__(512)
void gw_phase2h(const float* __restrict__ spikes, const float* __restrict__ bnd,
                float* __restrict__ mask, float* __restrict__ cov,
                int T, int N, float covval) {
  const int tid  = threadIdx.x;            // [0, 512)
  const int lane = tid & 63;
  const int wv   = tid >> 6;               // wave id [0,8)
  const int N4   = N >> 2;
  const int half = N4 >> 1;
  const float4* sp4 = (const float4*)spikes;
  f32x4* mk4 = (f32x4*)mask;

  __shared__ float ws1[8][64]; __shared__ int wi1s[8][64];
  __shared__ float ws2[8][64]; __shared__ int wi2s[8][64];
  __shared__ float wmx[8][64];
  __shared__ int gj1[8], gj2[8];

  const int chunk = blockIdx.x;
  float4 nmA = ((const float4*)bnd)[(size_t)chunk * N4 + tid];
  float4 nmB = ((const float4*)bnd)[(size_t)chunk * N4 + tid + half];
  const int baseA = tid * 4;
  const int baseB = baseA + (N >> 1);
  const int t00   = chunk * 16;
  const int cslot = wv * 8 + (lane >> 3);  // candidate slot (8-lane group id)

  // ---------- group 0: rows t00..t00+7 ----------
  float4 pA[4], pB[4], qA[4], qB[4];
#pragma unroll
  for (int r = 0; r < 4; ++r) {
    pA[r] = sp4[(size_t)(t00 + r) * N4 + tid];
    pB[r] = sp4[(size_t)(t00 + r) * N4 + tid + half];
  }
#pragma unroll
  for (int r = 0; r < 8; ++r) {
    const float4 s  = pA[r & 3];
    const float4 s2 = pB[r & 3];
    if (r < 4) {        // refill this ring slot with rows 4..7
      pA[r & 3] = sp4[(size_t)(t00 + r + 4) * N4 + tid];
      pB[r & 3] = sp4[(size_t)(t00 + r + 4) * N4 + tid + half];
    } else {            // HOIST: issue group 1's ring-init (rows 8..11) now
      qA[r - 4] = sp4[(size_t)(t00 + 8 + (r - 4)) * N4 + tid];
      qB[r - 4] = sp4[(size_t)(t00 + 8 + (r - 4)) * N4 + tid + half];
    }
    P2_ROW_BODY(s, s2, r);
  }
  __syncthreads();
  P2_TAIL(t00);
  __syncthreads();      // protect ws/gj reuse before group 1's pass A writes

  // ---------- group 1: rows t00+8..t00+15 (ring already in flight) ----------
#pragma unroll
  for (int r = 0; r < 8; ++r) {
    const float4 s  = qA[r & 3];
    const float4 s2 = qB[r & 3];
    if (r < 4) {        // refill with rows 12..15
      qA[r & 3] = sp4[(size_t)(t00 + 12 + r) * N4 + tid];
      qB[r & 3] = sp4[(size_t)(t00 + 12 + r) * N4 + tid + half];
    }
    P2_ROW_BODY(s, s2, r);
  }
  __syncthreads();
  P2_TAIL(t00 + 8);
}

// ---------------- Phase 2 (generic fallback, R13-proven): GR-row groups over L ----------------
template<int GR>
__global__ __launch_bounds__(512)
void gw_phase2(const float* __restrict__ spikes, const float* __restrict__ bnd,
               float* __restrict__ mask, float* __restrict__ cov,
               int T, int N, int L, float covval) {
  const int tid  = threadIdx.x;
  const int lane = tid & 63;
  const int wv   = tid >> 6;
  const int N4   = N >> 2;
  const int half = N4 >> 1;
  const float4* sp4 = (const float4*)spikes;
  f32x4* mk4 = (f32x4*)mask;

  __shared__ float ws1[GR][64]; __shared__ int wi1s[GR][64];
  __shared__ float ws2[GR][64]; __shared__ int wi2s[GR][64];
  __shared__ float wmx[GR][64];
  __shared__ int gj1[GR], gj2[GR];

  const int chunk = blockIdx.x;
  float4 nmA = ((const float4*)bnd)[(size_t)chunk * N4 + tid];
  float4 nmB = ((const float4*)bnd)[(size_t)chunk * N4 + tid + half];
  const int baseA = tid * 4;
  const int baseB = baseA + (N >> 1);
  const int t00   = chunk * L;
  const int cslot = wv * 8 + (lane >> 3);

  for (int g = 0; g < L; g += GR) {
    const int tg = t00 + g;
    float4 pA[4], pB[4];
#pragma unroll
    for (int r = 0; r < 4; ++r) {
      pA[r] = sp4[(size_t)(tg + r) * N4 + tid];
      pB[r] = sp4[(size_t)(tg + r) * N4 + tid + half];
    }
#pragma unroll
    for (int r = 0; r < GR; ++r) {
      const float4 s  = pA[r & 3];
      const float4 s2 = pB[r & 3];
      if (r < GR - 4) {
        pA[r & 3] = sp4[(size_t)(tg + r + 4) * N4 + tid];
        pB[r & 3] = sp4[(size_t)(tg + r + 4) * N4 + tid + half];
      }
      P2_ROW_BODY(s, s2, r);
    }
    __syncthreads();
#pragma unroll
    for (int rr = 0; rr < GR / 8; ++rr) {
      const int row = wv * (GR / 8) + rr;
      float a1 = ws1[row][lane]; int i1 = wi1s[row][lane];
      float a2 = ws2[row][lane]; int i2 = wi2s[row][lane];
      float gm = wmx[row][lane];
#pragma unroll
      for (int m = 1; m < 64; m <<= 1) {
        const float b1 = __shfl_xor(a1, m, 64); const int j1 = __shfl_xor(i1, m, 64);
        const float b2 = __shfl_xor(a2, m, 64); const int j2 = __shfl_xor(i2, m, 64);
        gm = fmaxf(gm, __shfl_xor(gm, m, 64));
        merge2(a1, i1, a2, i2, b1, j1, b2, j2);
      }
      if (lane == 0) {
        const int ig = (gm >= C_THR) ? 1 : 0;
        gj1[row] = ig ? i1 : -1;
        gj2[row] = ig ? i2 : -1;
        cov[tg + row] = ig ? covval : 0.0f;
      }
    }
    __syncthreads();
#pragma unroll
    for (int r = 0; r < GR; ++r) {
      const int j1 = gj1[r], j2 = gj2[r];
      f32x4 v, u;
      v.x = (j1 == baseA     || j2 == baseA)     ? 1.0f : 0.0f;
      v.y = (j1 == baseA + 1 || j2 == baseA + 1) ? 1.0f : 0.0f;
      v.z = (j1 == baseA + 2 || j2 == baseA + 2) ? 1.0f : 0.0f;
      v.w = (j1 == baseA + 3 || j2 == baseA + 3) ? 1.0f : 0.0f;
      u.x = (j1 == baseB     || j2 == baseB)     ? 1.0f : 0.0f;
      u.y = (j1 == baseB + 1 || j2 == baseB + 1) ? 1.0f : 0.0f;
      u.z = (j1 == baseB + 2 || j2 == baseB + 2) ? 1.0f : 0.0f;
      u.w = (j1 == baseB + 3 || j2 == baseB + 3) ? 1.0f : 0.0f;
      __builtin_nontemporal_store(v, &mk4[(size_t)(tg + r) * N4 + tid]);
      __builtin_nontemporal_store(u, &mk4[(size_t)(tg + r) * N4 + tid + half]);
    }
    if (g + GR < L) __syncthreads();
  }
}

extern "C" void kernel_launch(void* const* d_in, const int* in_sizes, int n_in,
                              void* d_out, int out_size, void* d_ws, size_t ws_size,
                              hipStream_t stream) {
  const float* spikes = (const float*)d_in[0];
  const float* nmda0  = (const float*)d_in[1];
  const int N = in_sizes[1];
  const int T = in_sizes[0] / N;

  float* out  = (float*)d_out;
  float* mask = out;                               // [T, N]
  float* cov  = out + (size_t)T * N;               // [T]
  float* nmf  = cov + T;                           // [N]
  const float covval = 2.0f / (float)N;

  // boundary-state chunk length L = 1<<Ls; Ls=4 (phase1-optimal), shrink if ws is small
  int Ls = 4;
  while (((size_t)(T >> Ls)) * (size_t)N * sizeof(float) > ws_size && Ls < 13) ++Ls;
  const int L = 1 << Ls;
  const int C = T >> Ls;
  float* bnd = (float*)d_ws;                       // [C, N]

  gw_phase1<<<N / NPB, 128, 0, stream>>>(spikes, nmda0, bnd, nmf, T, N, Ls);
  if (L == 16)
    gw_phase2h<<<C, 512, 0, stream>>>(spikes, bnd, mask, cov, T, N, covval);
  else if (L % 8 == 0 && L % 16 != 0)
    gw_phase2<8><<<C, 512, 0, stream>>>(spikes, bnd, mask, cov, T, N, L, covval);
  else
    gw_phase2<16><<<C, 512, 0, stream>>>(spikes, bnd, mask, cov, T, N, L, covval);
}

// Round 21
// 111.131 us; speedup vs baseline: 1.1297x; 1.0294x over previous
//
#include <hip/hip_runtime.h>
#include <cstdint>
#include <cstddef>

// ---- constants from the reference config (exact fp32 images of the Python doubles) ----
#define C_DECAY 0.99f   // (1.0 - alpha), alpha = 1.0/100.0
#define C_ALPHA 0.01f   // alpha
#define C_THR   0.58f   // IGNITE_THR
#define C_WTA   0.85f   // WTA_INH

#define NPB   16        // neurons per phase1 block (64B per spike row slice)
#define TILE  256       // timesteps per LDS tile (phase1); 16 KiB per buffer

// EMA step: EXACT replica of the reference op order. DO NOT rewrite algebraically
// (R10 lesson: fmaf substitution broke bitwise equality despite a paper proof).
#define EMA_STEP(x) nmda = __fadd_rn(__fmul_rn(C_DECAY, nmda), __fmul_rn(C_ALPHA, (x)))

typedef const __attribute__((address_space(1))) void g_void;
typedef __attribute__((address_space(3))) void l_void;
typedef float f32x4 __attribute__((ext_vector_type(4)));

// async global->LDS DMA, 16B/lane, wave-uniform LDS base (lane i lands at base + i*16)
__device__ __forceinline__ void gload_lds16(const float* g, float* l) {
  __builtin_amdgcn_global_load_lds((g_void*)g, (l_void*)l, 16, 0, 0);
}

// ---------------- Phase 1: [R11-verbatim, proven ~60us @ Ls=4 — DO NOT TOUCH] ----------------
// grid: N/16 = 256 blocks; block: 128 threads (wave0 = compute, wave1 = async loader)
// [R13/R14/R16/R18: five attempts to modify cost 18-32us each. Local optimum.]
__global__ __launch_bounds__(128)
void gw_phase1(const float* __restrict__ spikes, const float* __restrict__ nmda0,
               float* __restrict__ bnd, float* __restrict__ nmf,
               int T, int N, int Ls) {
  __shared__ float sb[2][TILE * NPB];   // 2 x 16 KiB, linear [step][neuron]
  const int w    = threadIdx.x >> 6;
  const int lane = threadIdx.x & 63;
  const int nblk = gridDim.x;                       // N/NPB
  const int bs   = (nblk % 8 == 0) ? ((blockIdx.x & 7) * (nblk >> 3) + (blockIdx.x >> 3))
                                   : (int)blockIdx.x;
  const int n0   = bs * NPB;
  const int ntiles = T / TILE;
  const int Lm1  = (1 << Ls) - 1;
  const int grow = lane >> 2;        // row within a 16-row DMA group
  const int gc   = (lane & 3) * 4;   // float column within the 16-float row

  if (w == 1) {   // prologue: stage tile 0 (16 x 1KiB async DMAs)
#pragma unroll
    for (int j = 0; j < TILE / 16; ++j)
      gload_lds16(spikes + (size_t)(j * 16 + grow) * N + n0 + gc, &sb[0][j * 256]);
  }
  __syncthreads();   // drains vmcnt -> tile 0 resident

  const int nn = lane & (NPB - 1);   // 4 lanes duplicate each neuron (broadcast reads)
  float nmda = 0.0f;
  if (w == 0) nmda = nmda0[n0 + nn];

  for (int tile = 0; tile < ntiles; ++tile) {
    const int cur = tile & 1;
    if (w == 0) {
      const float* buf = sb[cur];
      const int t0 = tile * TILE;
      float tA[16], tB[16];
#pragma unroll
      for (int i = 0; i < 16; ++i) tA[i] = buf[i * NPB + nn];
#pragma unroll
      for (int jp = 0; jp < TILE / 32; ++jp) {
        // even group: consume tA, prefetch odd group into tB
#pragma unroll
        for (int i = 0; i < 16; ++i) tB[i] = buf[((2 * jp + 1) * 16 + i) * NPB + nn];
        { const int tb = t0 + 2 * jp * 16;
          if ((tb & Lm1) == 0 && lane < NPB) bnd[(size_t)(tb >> Ls) * N + n0 + lane] = nmda; }
#pragma unroll
        for (int i = 0; i < 16; ++i) EMA_STEP(tA[i]);
        // odd group: consume tB, prefetch next even group into tA
        if (jp < TILE / 32 - 1) {
#pragma unroll
          for (int i = 0; i < 16; ++i) tA[i] = buf[((2 * jp + 2) * 16 + i) * NPB + nn];
        }
        { const int tb = t0 + (2 * jp + 1) * 16;
          if ((tb & Lm1) == 0 && lane < NPB) bnd[(size_t)(tb >> Ls) * N + n0 + lane] = nmda; }
#pragma unroll
        for (int i = 0; i < 16; ++i) EMA_STEP(tB[i]);
      }
    } else if (tile + 1 < ntiles) {
      const int t0 = (tile + 1) * TILE;
#pragma unroll
      for (int j = 0; j < TILE / 16; ++j)
        gload_lds16(spikes + (size_t)(t0 + j * 16 + grow) * N + n0 + gc, &sb[cur ^ 1][j * 256]);
    }
    __syncthreads();
  }
  if (w == 0 && lane < NPB) nmf[n0 + lane] = nmda;
}

// lexicographic merge of two (score desc, index asc) top-2 tuples
__device__ __forceinline__ void merge2(float& a1, int& i1, float& a2, int& i2,
                                       float b1, int j1, float b2, int j2) {
  const bool afirst = (a1 > b1) || (a1 == b1 && i1 < j1);
  const float w1 = afirst ? a1 : b1; const int wi1 = afirst ? i1 : j1;
  const float l1 = afirst ? b1 : a1; const int li1 = afirst ? j1 : i1;
  const float cc = afirst ? a2 : b2; const int ci  = afirst ? i2 : j2;
  const bool sfirst = (cc > l1) || (cc == l1 && ci < li1);
  a1 = w1; i1 = wi1;
  a2 = sfirst ? cc : l1; i2 = sfirst ? ci : li1;
}

// local stable top-2 update with a new (score, idx), idx processed in ascending order
#define LOCAL_TOP2(c, idx)                                         \
  if ((c) > a1) { a2 = a1; i2 = i1; a1 = (c); i1 = (idx); }        \
  else if ((c) > a2) { a2 = (c); i2 = (idx); }

// ---------------- Phase 2: GR=8 groups (proven structure), L=16 chunks [R15: 51.5us] ----------------
// 512 threads; pass A: 3-round partial butterfly -> 64 candidates/row; pass B: 1 row per wave.
template<int GR>
__global__ __launch_bounds__(512)
void gw_phase2(const float* __restrict__ spikes, const float* __restrict__ bnd,
               float* __restrict__ mask, float* __restrict__ cov,
               int T, int N, int L, float covval) {
  const int tid  = threadIdx.x;            // [0, 512)
  const int lane = tid & 63;
  const int wv   = tid >> 6;               // wave id [0,8)
  const int N4   = N >> 2;
  const int half = N4 >> 1;
  const float4* sp4 = (const float4*)spikes;
  f32x4* mk4 = (f32x4*)mask;

  __shared__ float ws1[GR][64]; __shared__ int wi1s[GR][64];
  __shared__ float ws2[GR][64]; __shared__ int wi2s[GR][64];
  __shared__ float wmx[GR][64];
  __shared__ int gj1[GR], gj2[GR];

  const int chunk = blockIdx.x;
  float4 nmA = ((const float4*)bnd)[(size_t)chunk * N4 + tid];
  float4 nmB = ((const float4*)bnd)[(size_t)chunk * N4 + tid + half];
  const int baseA = tid * 4;
  const int baseB = baseA + (N >> 1);
  const int t00   = chunk * L;
  const int cslot = wv * 8 + (lane >> 3);  // candidate slot (8-lane group id)

  for (int g = 0; g < L; g += GR) {
    const int tg = t00 + g;

    // ---------- pass A: GR rows, depth-4 ring prefetch, 3-round partial butterfly ----------
    float4 pA[4], pB[4];
#pragma unroll
    for (int r = 0; r < 4; ++r) {
      pA[r] = sp4[(size_t)(tg + r) * N4 + tid];
      pB[r] = sp4[(size_t)(tg + r) * N4 + tid + half];
    }
#pragma unroll
    for (int r = 0; r < GR; ++r) {
      const float4 s  = pA[r & 3];
      const float4 s2 = pB[r & 3];
      if (r < GR - 4) {   // refill the ring slot just consumed
        pA[r & 3] = sp4[(size_t)(tg + r + 4) * N4 + tid];
        pB[r & 3] = sp4[(size_t)(tg + r + 4) * N4 + tid + half];
      }

      // EXACT reference op order (no FMA, no reassociation)
      nmA.x = __fadd_rn(__fmul_rn(C_DECAY, nmA.x), __fmul_rn(C_ALPHA, s.x));
      nmA.y = __fadd_rn(__fmul_rn(C_DECAY, nmA.y), __fmul_rn(C_ALPHA, s.y));
      nmA.z = __fadd_rn(__fmul_rn(C_DECAY, nmA.z), __fmul_rn(C_ALPHA, s.z));
      nmA.w = __fadd_rn(__fmul_rn(C_DECAY, nmA.w), __fmul_rn(C_ALPHA, s.w));
      nmB.x = __fadd_rn(__fmul_rn(C_DECAY, nmB.x), __fmul_rn(C_ALPHA, s2.x));
      nmB.y = __fadd_rn(__fmul_rn(C_DECAY, nmB.y), __fmul_rn(C_ALPHA, s2.y));
      nmB.z = __fadd_rn(__fmul_rn(C_DECAY, nmB.z), __fmul_rn(C_ALPHA, s2.z));
      nmB.w = __fadd_rn(__fmul_rn(C_DECAY, nmB.w), __fmul_rn(C_ALPHA, s2.w));

      const float cA0 = __fmul_rn(nmA.x, C_WTA), cA1 = __fmul_rn(nmA.y, C_WTA);
      const float cA2 = __fmul_rn(nmA.z, C_WTA), cA3 = __fmul_rn(nmA.w, C_WTA);
      const float cB0 = __fmul_rn(nmB.x, C_WTA), cB1 = __fmul_rn(nmB.y, C_WTA);
      const float cB2 = __fmul_rn(nmB.z, C_WTA), cB3 = __fmul_rn(nmB.w, C_WTA);
      float mx = fmaxf(fmaxf(fmaxf(nmA.x, nmA.y), fmaxf(nmA.z, nmA.w)),
                       fmaxf(fmaxf(nmB.x, nmB.y), fmaxf(nmB.z, nmB.w)));

      float a1 = cA0; int i1 = baseA;
      float a2 = -__builtin_inff(); int i2 = 0x7fffffff;
      LOCAL_TOP2(cA1, baseA + 1); LOCAL_TOP2(cA2, baseA + 2); LOCAL_TOP2(cA3, baseA + 3);
      LOCAL_TOP2(cB0, baseB);     LOCAL_TOP2(cB1, baseB + 1);
      LOCAL_TOP2(cB2, baseB + 2); LOCAL_TOP2(cB3, baseB + 3);

      // partial butterfly: 3 rounds -> each 8-lane group holds its merged top-2
#pragma unroll
      for (int m = 1; m < 8; m <<= 1) {
        const float b1 = __shfl_xor(a1, m, 64); const int j1 = __shfl_xor(i1, m, 64);
        const float b2 = __shfl_xor(a2, m, 64); const int j2 = __shfl_xor(i2, m, 64);
        mx = fmaxf(mx, __shfl_xor(mx, m, 64));
        merge2(a1, i1, a2, i2, b1, j1, b2, j2);
      }
      if ((lane & 7) == 0) {
        ws1[r][cslot] = a1; wi1s[r][cslot] = i1;
        ws2[r][cslot] = a2; wi2s[r][cslot] = i2;
        wmx[r][cslot] = mx;
      }
    }
    __syncthreads();

    // ---------- pass B: each wave finishes GR/8 rows (64 candidates, 6-round butterfly) ----------
#pragma unroll
    for (int rr = 0; rr < GR / 8; ++rr) {
      const int row = wv * (GR / 8) + rr;
      float a1 = ws1[row][lane]; int i1 = wi1s[row][lane];
      float a2 = ws2[row][lane]; int i2 = wi2s[row][lane];
      float gm = wmx[row][lane];
#pragma unroll
      for (int m = 1; m < 64; m <<= 1) {
        const float b1 = __shfl_xor(a1, m, 64); const int j1 = __shfl_xor(i1, m, 64);
        const float b2 = __shfl_xor(a2, m, 64); const int j2 = __shfl_xor(i2, m, 64);
        gm = fmaxf(gm, __shfl_xor(gm, m, 64));
        merge2(a1, i1, a2, i2, b1, j1, b2, j2);
      }
      if (lane == 0) {
        const int ig = (gm >= C_THR) ? 1 : 0;
        gj1[row] = ig ? i1 : -1;        // -1 sentinel: nothing matches -> zero row
        gj2[row] = ig ? i2 : -1;
        cov[tg + row] = ig ? covval : 0.0f;
      }
    }
    __syncthreads();

    // ---------- pass C: stream out GR mask rows (nontemporal) ----------
#pragma unroll
    for (int r = 0; r < GR; ++r) {
      const int j1 = gj1[r], j2 = gj2[r];
      f32x4 v, u;
      v.x = (j1 == baseA     || j2 == baseA)     ? 1.0f : 0.0f;
      v.y = (j1 == baseA + 1 || j2 == baseA + 1) ? 1.0f : 0.0f;
      v.z = (j1 == baseA + 2 || j2 == baseA + 2) ? 1.0f : 0.0f;
      v.w = (j1 == baseA + 3 || j2 == baseA + 3) ? 1.0f : 0.0f;
      u.x = (j1 == baseB     || j2 == baseB)     ? 1.0f : 0.0f;
      u.y = (j1 == baseB + 1 || j2 == baseB + 1) ? 1.0f : 0.0f;
      u.z = (j1 == baseB + 2 || j2 == baseB + 2) ? 1.0f : 0.0f;
      u.w = (j1 == baseB + 3 || j2 == baseB + 3) ? 1.0f : 0.0f;
      __builtin_nontemporal_store(v, &mk4[(size_t)(tg + r) * N4 + tid]);
      __builtin_nontemporal_store(u, &mk4[(size_t)(tg + r) * N4 + tid + half]);
    }
    if (g + GR < L) __syncthreads();
  }
}

extern "C" void kernel_launch(void* const* d_in, const int* in_sizes, int n_in,
                              void* d_out, int out_size, void* d_ws, size_t ws_size,
                              hipStream_t stream) {
  const float* spikes = (const float*)d_in[0];
  const float* nmda0  = (const float*)d_in[1];
  const int N = in_sizes[1];
  const int T = in_sizes[0] / N;

  float* out  = (float*)d_out;
  float* mask = out;                               // [T, N]
  float* cov  = out + (size_t)T * N;               // [T]
  float* nmf  = cov + T;                           // [N]

  // boundary-state chunk length L = 1<<Ls; Ls=4 (phase1-optimal), shrink if ws is small
  int Ls = 4;
  while (((size_t)(T >> Ls)) * (size_t)N * sizeof(float) > ws_size && Ls < 13) ++Ls;
  const int L = 1 << Ls;
  const int C = T >> Ls;
  float* bnd = (float*)d_ws;                       // [C, N]
  const float covval = 2.0f / (float)N;

  gw_phase1<<<N / NPB, 128, 0, stream>>>(spikes, nmda0, bnd, nmf, T, N, Ls);
  if (L % 8 == 0) gw_phase2<8><<<C, 512, 0, stream>>>(spikes, bnd, mask, cov, T, N, L, covval);
  else            gw_phase2<16><<<C, 512, 0, stream>>>(spikes, bnd, mask, cov, T, N, L, covval);
}